// Round 1
// baseline (657.853 us; speedup 1.0000x reference)
//
#include <hip/hip_runtime.h>

typedef __bf16  bf16x4 __attribute__((ext_vector_type(4)));
typedef __bf16  bf16x8 __attribute__((ext_vector_type(8)));
typedef float   f32x4  __attribute__((ext_vector_type(4)));

constexpr int BM = 128, BN = 128, BK = 32;
constexpr int LDT = BK + 8;   // pad 8 shorts (16B): 80B row stride -> 2-way max bank conflict (free)

__device__ inline bf16x8 load8(const __bf16* p) {
    bf16x4 lo = *reinterpret_cast<const bf16x4*>(p);
    bf16x4 hi = *reinterpret_cast<const bf16x4*>(p + 4);
    return __builtin_shufflevector(lo, hi, 0, 1, 2, 3, 4, 5, 6, 7);
}
__device__ inline void store8(__bf16* p, bf16x8 v) {
    *reinterpret_cast<bf16x4*>(p)     = __builtin_shufflevector(v, v, 0, 1, 2, 3);
    *reinterpret_cast<bf16x4*>(p + 4) = __builtin_shufflevector(v, v, 4, 5, 6, 7);
}

// ---------------------------------------------------------------------------
// NT GEMM: C[m,n] = sum_k A[m,k] * Bt[n,k]   (A:[M,K], Bt:[N,K], row-major bf16)
// EPI: 0 = f32 store, 1 = bf16 store, 2 = +bias,leakyRelu -> bf16, 3 = +bias -> f32
// CMODE: 0 none, 1 = causal tile-skip (scores), 2 = causal K-limit (PV; A rows q, k keys)
// Requires M%128==0, N%128==0, K%32==0.
// ---------------------------------------------------------------------------
template<int EPI, int CMODE>
__launch_bounds__(256)
__global__ void gemm_nt(const __bf16* __restrict__ Aall, const __bf16* __restrict__ Ball,
                        const float* __restrict__ bias, void* __restrict__ Call,
                        int M, int N, int K, long sA, long sB, long sC)
{
    const int m0 = blockIdx.y * BM;
    const int n0 = blockIdx.x * BN;
    if (CMODE == 1 && n0 >= m0 + BM) return;          // tile entirely above causal diagonal
    int Kend = K;
    if (CMODE == 2) Kend = min(K, m0 + BM);           // P is exactly 0 for k > q

    const __bf16* A  = Aall + (long)blockIdx.z * sA;
    const __bf16* Bt = Ball + (long)blockIdx.z * sB;

    __shared__ alignas(16) __bf16 As[BM * LDT];
    __shared__ alignas(16) __bf16 Bs[BN * LDT];

    const int tid  = threadIdx.x;
    const int wave = tid >> 6, lane = tid & 63;
    const int wm   = (wave >> 1) * 64, wn = (wave & 1) * 64;
    const int quad = lane >> 4, l16 = lane & 15;

    f32x4 acc[4][4];
    #pragma unroll
    for (int i = 0; i < 4; i++)
        #pragma unroll
        for (int j = 0; j < 4; j++) { f32x4 z = {0.f, 0.f, 0.f, 0.f}; acc[i][j] = z; }

    const int r0 = tid >> 2;          // 0..63 : staging row
    const int k8 = (tid & 3) * 8;     // 0,8,16,24

    for (int k0 = 0; k0 < Kend; k0 += BK) {
        bf16x8 a0 = *reinterpret_cast<const bf16x8*>(A  + (long)(m0 + r0)      * K + k0 + k8);
        bf16x8 a1 = *reinterpret_cast<const bf16x8*>(A  + (long)(m0 + r0 + 64) * K + k0 + k8);
        bf16x8 b0 = *reinterpret_cast<const bf16x8*>(Bt + (long)(n0 + r0)      * K + k0 + k8);
        bf16x8 b1 = *reinterpret_cast<const bf16x8*>(Bt + (long)(n0 + r0 + 64) * K + k0 + k8);
        __syncthreads();                              // previous iteration's LDS reads done
        store8(&As[r0 * LDT + k8], a0);
        store8(&As[(r0 + 64) * LDT + k8], a1);
        store8(&Bs[r0 * LDT + k8], b0);
        store8(&Bs[(r0 + 64) * LDT + k8], b1);
        __syncthreads();

        bf16x8 af[4], bff[4];
        #pragma unroll
        for (int i = 0; i < 4; i++) {
            af[i]  = load8(&As[(wm + i * 16 + l16) * LDT + quad * 8]);
            bff[i] = load8(&Bs[(wn + i * 16 + l16) * LDT + quad * 8]);
        }
        #pragma unroll
        for (int i = 0; i < 4; i++)
            #pragma unroll
            for (int j = 0; j < 4; j++)
                acc[i][j] = __builtin_amdgcn_mfma_f32_16x16x32_bf16(af[i], bff[j], acc[i][j], 0, 0, 0);
    }

    const long cb = (long)blockIdx.z * sC;
    #pragma unroll
    for (int j = 0; j < 4; j++) {
        const int col = n0 + wn + j * 16 + l16;
        float bv = 0.f;
        if (EPI == 2 || EPI == 3) bv = bias[col];
        #pragma unroll
        for (int i = 0; i < 4; i++) {
            #pragma unroll
            for (int r = 0; r < 4; r++) {
                const int row = m0 + wm + i * 16 + quad * 4 + r;  // C/D: row=(lane>>4)*4+reg, col=lane&15
                float c = acc[i][j][r];
                if (EPI == 2) { c += bv; c = c > 0.f ? c : 0.2f * c; }
                if (EPI == 3) { c += bv; }
                if (EPI == 0 || EPI == 3)
                    reinterpret_cast<float*>(Call)[cb + (long)row * N + col] = c;
                else
                    reinterpret_cast<__bf16*>(Call)[cb + (long)row * N + col] = (__bf16)c;
            }
        }
    }
}

// ---------------------------------------------------------------------------
// Row softmax in-place on bf16 scores [B][S][S]; assumes S==4096, block=256.
// Applies scale; causal writes exact 0 beyond the diagonal (enables PV K-limit).
// ---------------------------------------------------------------------------
template<bool CAUSAL>
__launch_bounds__(256)
__global__ void softmax_inplace(__bf16* __restrict__ SC, int S_, float scale)
{
    const int r = blockIdx.x;
    __bf16* rowp = SC + ((long)blockIdx.y * S_ + r) * S_;
    const int tid = threadIdx.x;
    const int nvalid = CAUSAL ? r + 1 : S_;

    float v[16];
    float mx = -1e30f;
    #pragma unroll
    for (int i = 0; i < 16; i++) {
        int c = tid + i * 256;
        float val = (c < nvalid) ? (float)rowp[c] * scale : -1e30f;
        v[i] = val; mx = fmaxf(mx, val);
    }
    #pragma unroll
    for (int off = 32; off; off >>= 1) mx = fmaxf(mx, __shfl_xor(mx, off));
    __shared__ float redm[4], reds[4];
    const int wave = tid >> 6, lane = tid & 63;
    if (lane == 0) redm[wave] = mx;
    __syncthreads();
    mx = fmaxf(fmaxf(redm[0], redm[1]), fmaxf(redm[2], redm[3]));

    float sum = 0.f;
    #pragma unroll
    for (int i = 0; i < 16; i++) { float e = __expf(v[i] - mx); v[i] = e; sum += e; }
    #pragma unroll
    for (int off = 32; off; off >>= 1) sum += __shfl_xor(sum, off);
    if (lane == 0) reds[wave] = sum;
    __syncthreads();
    sum = reds[0] + reds[1] + reds[2] + reds[3];
    const float inv = 1.f / sum;
    #pragma unroll
    for (int i = 0; i < 16; i++) rowp[tid + i * 256] = (__bf16)(v[i] * inv);  // masked -> exact 0
}

// ---------------------------------------------------------------------------
// Residual + LayerNorm over D=256. One wave per row; optional bf16 mirror.
// ---------------------------------------------------------------------------
__launch_bounds__(256)
__global__ void ln_res(const float* __restrict__ a, const float* __restrict__ b,
                       const float* __restrict__ gamma, const float* __restrict__ beta,
                       float* __restrict__ outf, __bf16* __restrict__ outb)
{
    const int row  = blockIdx.x * 4 + (threadIdx.x >> 6);
    const int lane = threadIdx.x & 63;
    const float4 va = reinterpret_cast<const float4*>(a)[row * 64 + lane];
    const float4 vb = reinterpret_cast<const float4*>(b)[row * 64 + lane];
    float x0 = va.x + vb.x, x1 = va.y + vb.y, x2 = va.z + vb.z, x3 = va.w + vb.w;
    float s = x0 + x1 + x2 + x3;
    #pragma unroll
    for (int off = 32; off; off >>= 1) s += __shfl_xor(s, off);
    const float mu = s * (1.f / 256.f);
    float d0 = x0 - mu, d1 = x1 - mu, d2 = x2 - mu, d3 = x3 - mu;
    float s2 = d0 * d0 + d1 * d1 + d2 * d2 + d3 * d3;
    #pragma unroll
    for (int off = 32; off; off >>= 1) s2 += __shfl_xor(s2, off);
    const float rs = rsqrtf(s2 * (1.f / 256.f) + 1e-3f);
    const float4 g  = reinterpret_cast<const float4*>(gamma)[lane];
    const float4 be = reinterpret_cast<const float4*>(beta)[lane];
    float o0 = d0 * rs * g.x + be.x, o1 = d1 * rs * g.y + be.y;
    float o2 = d2 * rs * g.z + be.z, o3 = d3 * rs * g.w + be.w;
    float4 o; o.x = o0; o.y = o1; o.z = o2; o.w = o3;
    reinterpret_cast<float4*>(outf)[row * 64 + lane] = o;
    if (outb) {
        bf16x4 ob; ob[0] = (__bf16)o0; ob[1] = (__bf16)o1; ob[2] = (__bf16)o2; ob[3] = (__bf16)o3;
        reinterpret_cast<bf16x4*>(outb)[row * 64 + lane] = ob;
    }
}

// fp32 -> bf16, 4 elems/thread
__global__ void f2b4(const float4* __restrict__ in, bf16x4* __restrict__ out, long n4)
{
    long i = (long)blockIdx.x * blockDim.x + threadIdx.x;
    if (i < n4) {
        float4 v = in[i];
        bf16x4 o; o[0] = (__bf16)v.x; o[1] = (__bf16)v.y; o[2] = (__bf16)v.z; o[3] = (__bf16)v.w;
        out[i] = o;
    }
}

// dst[colsP][rowsP] = transpose(src[rows][cols]) zero-padded, fp32->bf16 (tiny weights)
__global__ void transpose_pad(const float* __restrict__ src, __bf16* __restrict__ dst,
                              int rows, int cols, int rowsP, int colsP)
{
    int i = blockIdx.x * 256 + threadIdx.x;
    if (i >= rowsP * colsP) return;
    int c = i / rowsP, r = i % rowsP;
    float v = (r < rows && c < cols) ? src[r * cols + c] : 0.f;
    dst[i] = (__bf16)v;
}

__global__ void pad_bias(const float* __restrict__ b, float* __restrict__ bp, int n, int np)
{
    int i = blockIdx.x * 256 + threadIdx.x;
    if (i < np) bp[i] = (i < n) ? b[i] : 0.f;
}

// per-batch bf16 transpose: out[b][cols][rows] = in[b][rows][cols]
__global__ void transpose_bf(const __bf16* __restrict__ in, __bf16* __restrict__ out,
                             int rows, int cols)
{
    __shared__ __bf16 t[32][33];
    const long base = (long)blockIdx.z * rows * cols;
    const int c0 = blockIdx.x * 32, r0 = blockIdx.y * 32;
    const int tx = threadIdx.x & 31, ty = threadIdx.x >> 5;
    #pragma unroll
    for (int i = 0; i < 32; i += 8)
        t[ty + i][tx] = in[base + (long)(r0 + ty + i) * cols + (c0 + tx)];
    __syncthreads();
    #pragma unroll
    for (int i = 0; i < 32; i += 8)
        out[base + (long)(c0 + ty + i) * rows + (r0 + tx)] = t[tx][ty + i];
}

extern "C" void kernel_launch(void* const* d_in, const int* in_sizes, int n_in,
                              void* d_out, int out_size, void* d_ws, size_t ws_size,
                              hipStream_t stream)
{
    constexpr int B = 4, S = 4096, D = 256, H = 400, Hp = 512;
    constexpr int R = B * S;
    constexpr float SCALE = 1.f / 64.f;   // 1/sqrt(4096)

    const float* inputs = (const float*)d_in[0];
    const float* ctx    = (const float*)d_in[1];
    const float* sa_Wk  = (const float*)d_in[2];
    const float* sa_Wv  = (const float*)d_in[3];
    const float* sa_Wq  = (const float*)d_in[4];
    const float* ca_Wk  = (const float*)d_in[5];
    const float* ca_Wv  = (const float*)d_in[6];
    const float* ca_Wq  = (const float*)d_in[7];
    const float* W1     = (const float*)d_in[8];
    const float* b1     = (const float*)d_in[9];
    const float* W2     = (const float*)d_in[10];
    const float* b2     = (const float*)d_in[11];
    const float* gamma  = (const float*)d_in[12];
    const float* beta   = (const float*)d_in[13];
    float* out = (float*)d_out;

    char* ws = (char*)d_ws;
    size_t off = 0;
    auto alloc = [&](size_t bytes) -> char* {
        char* p = ws + off; off += (bytes + 255) & ~size_t(255); return p;
    };
    __bf16* bfA  = (__bf16*)alloc((size_t)R * D * 2);   // bf16(inputs); reused as xbf after self-attn
    __bf16* bfC  = (__bf16*)alloc((size_t)R * D * 2);   // bf16(context); reused as ybf after cross-attn
    __bf16* Qb   = (__bf16*)alloc((size_t)R * D * 2);
    __bf16* Kb   = (__bf16*)alloc((size_t)R * D * 2);
    __bf16* Vt   = (__bf16*)alloc((size_t)B * D * S * 2);  // [B][D][S]
    __bf16* h    = (__bf16*)alloc((size_t)R * Hp * 2);     // FFN hidden; reused as Vtmp earlier
    float*  attn = (float*)alloc((size_t)R * D * 4);       // attention out; reused as ff later
    float*  x    = (float*)alloc((size_t)R * D * 4);
    float*  y    = (float*)alloc((size_t)R * D * 4);
    __bf16* wq_s = (__bf16*)alloc((size_t)D * D * 2);
    __bf16* wk_s = (__bf16*)alloc((size_t)D * D * 2);
    __bf16* wv_s = (__bf16*)alloc((size_t)D * D * 2);
    __bf16* wq_c = (__bf16*)alloc((size_t)D * D * 2);
    __bf16* wk_c = (__bf16*)alloc((size_t)D * D * 2);
    __bf16* wv_c = (__bf16*)alloc((size_t)D * D * 2);
    __bf16* W1t  = (__bf16*)alloc((size_t)Hp * D * 2);     // [Hp][D], rows >=400 zero
    __bf16* W2t  = (__bf16*)alloc((size_t)D * Hp * 2);     // [D][Hp], cols >=400 zero
    float*  b1p  = (float*)alloc((size_t)Hp * 4);

    // scores buffer last: batched (all 4 batches, 128 MiB) if workspace allows
    const size_t scBatched = (size_t)B * S * S * 2;
    const size_t scSingle  = (size_t)S * S * 2;
    bool batched = (off + scBatched) <= ws_size;
    if (!batched && (off + scSingle) > ws_size) return;    // workspace too small: give up loudly
    __bf16* SC = (__bf16*)(ws + off);

    __bf16* xbf  = bfA;
    __bf16* ybf  = bfC;
    __bf16* Vtmp = h;
    float*  ff   = attn;

    const dim3 blk(256);
    const dim3 gProj(D / BN, R / BM, 1);
    const dim3 gT(D / 32, S / 32, B);

    // --- prep: converts + weight transposes ---
    f2b4<<<R * D / 1024, blk, 0, stream>>>((const float4*)inputs, (bf16x4*)bfA, (long)R * D / 4);
    f2b4<<<R * D / 1024, blk, 0, stream>>>((const float4*)ctx,    (bf16x4*)bfC, (long)R * D / 4);
    transpose_pad<<<(D * D + 255) / 256, blk, 0, stream>>>(sa_Wq, wq_s, D, D, D, D);
    transpose_pad<<<(D * D + 255) / 256, blk, 0, stream>>>(sa_Wk, wk_s, D, D, D, D);
    transpose_pad<<<(D * D + 255) / 256, blk, 0, stream>>>(sa_Wv, wv_s, D, D, D, D);
    transpose_pad<<<(D * D + 255) / 256, blk, 0, stream>>>(ca_Wq, wq_c, D, D, D, D);
    transpose_pad<<<(D * D + 255) / 256, blk, 0, stream>>>(ca_Wk, wk_c, D, D, D, D);
    transpose_pad<<<(D * D + 255) / 256, blk, 0, stream>>>(ca_Wv, wv_c, D, D, D, D);
    transpose_pad<<<(Hp * D + 255) / 256, blk, 0, stream>>>(W1, W1t, D, H, D, Hp);
    transpose_pad<<<(D * Hp + 255) / 256, blk, 0, stream>>>(W2, W2t, H, D, Hp, D);
    pad_bias<<<2, blk, 0, stream>>>(b1, b1p, H, Hp);

    // --- self-attention (causal) ---
    gemm_nt<1, 0><<<gProj, blk, 0, stream>>>(bfA, wq_s, nullptr, Qb,   R, D, D, 0, 0, 0);
    gemm_nt<1, 0><<<gProj, blk, 0, stream>>>(bfA, wk_s, nullptr, Kb,   R, D, D, 0, 0, 0);
    gemm_nt<1, 0><<<gProj, blk, 0, stream>>>(bfA, wv_s, nullptr, Vtmp, R, D, D, 0, 0, 0);
    transpose_bf<<<gT, blk, 0, stream>>>(Vtmp, Vt, S, D);
    if (batched) {
        gemm_nt<1, 1><<<dim3(S / BN, S / BM, B), blk, 0, stream>>>(Qb, Kb, nullptr, SC, S, S, D,
                                                                   (long)S * D, (long)S * D, (long)S * S);
        softmax_inplace<true><<<dim3(S, B), blk, 0, stream>>>(SC, S, SCALE);
        gemm_nt<0, 2><<<dim3(D / BN, S / BM, B), blk, 0, stream>>>(SC, Vt, nullptr, attn, S, D, S,
                                                                   (long)S * S, (long)D * S, (long)S * D);
    } else {
        for (int b = 0; b < B; b++) {
            gemm_nt<1, 1><<<dim3(S / BN, S / BM, 1), blk, 0, stream>>>(Qb + (long)b * S * D, Kb + (long)b * S * D,
                                                                       nullptr, SC, S, S, D, 0, 0, 0);
            softmax_inplace<true><<<dim3(S, 1), blk, 0, stream>>>(SC, S, SCALE);
            gemm_nt<0, 2><<<dim3(D / BN, S / BM, 1), blk, 0, stream>>>(SC, Vt + (long)b * D * S, nullptr,
                                                                       attn + (long)b * S * D, S, D, S, 0, 0, 0);
        }
    }
    ln_res<<<R / 4, blk, 0, stream>>>(attn, inputs, gamma, beta, x, xbf);

    // --- cross-attention (full) ---
    gemm_nt<1, 0><<<gProj, blk, 0, stream>>>(xbf, wq_c, nullptr, Qb,   R, D, D, 0, 0, 0);
    gemm_nt<1, 0><<<gProj, blk, 0, stream>>>(bfC, wk_c, nullptr, Kb,   R, D, D, 0, 0, 0);
    gemm_nt<1, 0><<<gProj, blk, 0, stream>>>(bfC, wv_c, nullptr, Vtmp, R, D, D, 0, 0, 0);
    transpose_bf<<<gT, blk, 0, stream>>>(Vtmp, Vt, S, D);
    if (batched) {
        gemm_nt<1, 0><<<dim3(S / BN, S / BM, B), blk, 0, stream>>>(Qb, Kb, nullptr, SC, S, S, D,
                                                                   (long)S * D, (long)S * D, (long)S * S);
        softmax_inplace<false><<<dim3(S, B), blk, 0, stream>>>(SC, S, SCALE);
        gemm_nt<0, 0><<<dim3(D / BN, S / BM, B), blk, 0, stream>>>(SC, Vt, nullptr, attn, S, D, S,
                                                                   (long)S * S, (long)D * S, (long)S * D);
    } else {
        for (int b = 0; b < B; b++) {
            gemm_nt<1, 0><<<dim3(S / BN, S / BM, 1), blk, 0, stream>>>(Qb + (long)b * S * D, Kb + (long)b * S * D,
                                                                       nullptr, SC, S, S, D, 0, 0, 0);
            softmax_inplace<false><<<dim3(S, 1), blk, 0, stream>>>(SC, S, SCALE);
            gemm_nt<0, 0><<<dim3(D / BN, S / BM, 1), blk, 0, stream>>>(SC, Vt + (long)b * D * S, nullptr,
                                                                       attn + (long)b * S * D, S, D, S, 0, 0, 0);
        }
    }
    ln_res<<<R / 4, blk, 0, stream>>>(attn, x, gamma, beta, y, ybf);

    // --- FFN ---
    gemm_nt<2, 0><<<dim3(Hp / BN, R / BM, 1), blk, 0, stream>>>(ybf, W1t, b1p, h, R, Hp, D, 0, 0, 0);
    gemm_nt<3, 0><<<dim3(D / BN, R / BM, 1), blk, 0, stream>>>(h, W2t, b2, ff, R, D, Hp, 0, 0, 0);
    ln_res<<<R / 4, blk, 0, stream>>>(ff, y, gamma, beta, out, nullptr);
}

// Round 2
// 561.561 us; speedup vs baseline: 1.1715x; 1.1715x over previous
//
#include <hip/hip_runtime.h>

typedef __bf16  bf16x4 __attribute__((ext_vector_type(4)));
typedef __bf16  bf16x8 __attribute__((ext_vector_type(8)));
typedef float   f32x4  __attribute__((ext_vector_type(4)));
typedef unsigned int u32;

constexpr int BM = 128, BN = 128, BK = 32;

// async global->LDS, 16B per lane. LDS dest is wave-uniform base + lane*16.
__device__ __forceinline__ void async_cp16(const __bf16* g, __bf16* lds) {
    __builtin_amdgcn_global_load_lds(
        (const __attribute__((address_space(1))) u32*)g,
        (__attribute__((address_space(3))) u32*)lds, 16, 0, 0);
}

// swizzled LDS offset (in shorts) of (row, 16B-slot q): conflict-free ds_read_b128
__device__ __forceinline__ int swz(int row, int q) {
    return row * BK + (((q + (row >> 1)) & 3) << 3);
}

// ---------------------------------------------------------------------------
// NT GEMM: C[m,n] = sum_k A[m,k] * Bt[n,k]   (A:[M,K], Bt:[N,K], row-major bf16)
// EPI: 0 = f32 store (split-K partial at C0+chunk*pstrideB), 1 = bf16 store,
//      2 = +bias,leakyRelu -> bf16, 4 = bf16 split across C0/C1/C2 by col/256
// CMODE: 0 none, 1 causal tile-skip (scores), 2 causal K-limit (PV)
// ---------------------------------------------------------------------------
template<int EPI, int CMODE>
__launch_bounds__(256)
__global__ void gemm_nt(const __bf16* __restrict__ Aall, const __bf16* __restrict__ Ball,
                        const float* __restrict__ bias,
                        void* __restrict__ C0, void* __restrict__ C1, void* __restrict__ C2,
                        int N, int K, long sA, long sB, long sC,
                        int nTx, int klen, long pstrideB)
{
    const int chunk = blockIdx.x / nTx;
    const int n0 = (blockIdx.x - chunk * nTx) * BN;
    const int m0 = blockIdx.y * BM;
    if (CMODE == 1 && n0 >= m0 + BM) return;          // tile above causal diagonal
    const int kbase = chunk * klen;
    int kend = kbase + klen;
    if (CMODE == 2) kend = min(kend, m0 + BM);        // softmax wrote exact 0 for k > q
    const int klocal = kend - kbase;                  // may be <= 0 (writes zeros)

    const __bf16* A  = Aall + (long)blockIdx.z * sA;
    const __bf16* Bt = Ball + (long)blockIdx.z * sB;

    __shared__ alignas(16) __bf16 As[BM * BK];
    __shared__ alignas(16) __bf16 Bs[BN * BK];

    const int tid = threadIdx.x;
    const int wave = tid >> 6, lane = tid & 63;
    const int wm = (wave >> 1) * 64, wn = (wave & 1) * 64;
    const int quad = lane >> 4, l16 = lane & 15;

    // staging: 2 rounds x 256 lanes x 16B per matrix; LDS slot u = r*256+tid
    const int row0 = tid >> 2, sl0 = tid & 3;
    const int ks0 = (sl0 - (row0 >> 1)) & 3;
    const int row1 = row0 + 64;
    const int ks1 = (sl0 - (row1 >> 1)) & 3;
    const __bf16* gA0 = A  + (long)(m0 + row0) * K + kbase + ks0 * 8;
    const __bf16* gA1 = A  + (long)(m0 + row1) * K + kbase + ks1 * 8;
    const __bf16* gB0 = Bt + (long)(n0 + row0) * K + kbase + ks0 * 8;
    const __bf16* gB1 = Bt + (long)(n0 + row1) * K + kbase + ks1 * 8;
    __bf16* ldsA0 = As + wave * 512;            // wave-uniform base; lane l -> +l*16B
    __bf16* ldsA1 = As + 2048 + wave * 512;
    __bf16* ldsB0 = Bs + wave * 512;
    __bf16* ldsB1 = Bs + 2048 + wave * 512;

    f32x4 acc[4][4];
    #pragma unroll
    for (int i = 0; i < 4; i++)
        #pragma unroll
        for (int j = 0; j < 4; j++) { f32x4 z = {0.f, 0.f, 0.f, 0.f}; acc[i][j] = z; }

    for (int kk = 0; kk < klocal; kk += BK) {
        __syncthreads();                         // prev iter's ds_reads done
        async_cp16(gA0, ldsA0);
        async_cp16(gA1, ldsA1);
        async_cp16(gB0, ldsB0);
        async_cp16(gB1, ldsB1);
        gA0 += BK; gA1 += BK; gB0 += BK; gB1 += BK;
        __syncthreads();                         // vmcnt(0) drain -> LDS populated

        bf16x8 af[4], bg[4];
        #pragma unroll
        for (int i = 0; i < 4; i++) {
            af[i] = *(const bf16x8*)(As + swz(wm + i * 16 + l16, quad));
            bg[i] = *(const bf16x8*)(Bs + swz(wn + i * 16 + l16, quad));
        }
        #pragma unroll
        for (int i = 0; i < 4; i++)
            #pragma unroll
            for (int j = 0; j < 4; j++)
                acc[i][j] = __builtin_amdgcn_mfma_f32_16x16x32_bf16(af[i], bg[j], acc[i][j], 0, 0, 0);
    }

    char* cb = (char*)C0 + (long)chunk * pstrideB;
    #pragma unroll
    for (int j = 0; j < 4; j++) {
        const int col = n0 + wn + j * 16 + l16;
        const float bv = (EPI == 2) ? bias[col] : 0.f;
        #pragma unroll
        for (int i = 0; i < 4; i++) {
            #pragma unroll
            for (int r = 0; r < 4; r++) {
                const int row = m0 + wm + i * 16 + quad * 4 + r;  // C/D: row=(lane>>4)*4+reg
                float c = acc[i][j][r];
                if (EPI == 2) { c += bv; c = c > 0.f ? c : 0.2f * c; }
                if (EPI == 0)
                    ((float*)cb)[(long)blockIdx.z * sC + (long)row * N + col] = c;
                else if (EPI == 1)
                    ((__bf16*)cb)[(long)blockIdx.z * sC + (long)row * N + col] = (__bf16)c;
                else if (EPI == 2)
                    ((__bf16*)cb)[(long)row * N + col] = (__bf16)c;
                else {  // EPI == 4: split by column segment of 256
                    const int seg = col >> 8;
                    __bf16* dst = seg == 0 ? (__bf16*)C0 : (seg == 1 ? (__bf16*)C1 : (__bf16*)C2);
                    dst[(long)row * 256 + (col & 255)] = (__bf16)c;
                }
            }
        }
    }
}

// Row softmax in-place on bf16 scores [B][S][S]; S==4096, vectorized loads.
template<bool CAUSAL>
__launch_bounds__(256)
__global__ void softmax_inplace(__bf16* __restrict__ SC, float scale)
{
    const int r = blockIdx.x;
    bf16x8* rowp = (bf16x8*)(SC + ((long)blockIdx.y * 4096 + r) * 4096);
    const int tid = threadIdx.x;
    const int nvalid = CAUSAL ? r + 1 : 4096;

    bf16x8 va = rowp[2 * tid], vb = rowp[2 * tid + 1];
    const int c0 = tid * 16;
    float v[16];
    float mx = -1e30f;
    #pragma unroll
    for (int j = 0; j < 8; j++) {
        v[j]     = (c0 + j     < nvalid) ? (float)va[j] * scale : -1e30f;
        v[j + 8] = (c0 + 8 + j < nvalid) ? (float)vb[j] * scale : -1e30f;
    }
    #pragma unroll
    for (int j = 0; j < 16; j++) mx = fmaxf(mx, v[j]);
    #pragma unroll
    for (int off = 32; off; off >>= 1) mx = fmaxf(mx, __shfl_xor(mx, off));
    __shared__ float redm[4], reds[4];
    const int wave = tid >> 6, lane = tid & 63;
    if (lane == 0) redm[wave] = mx;
    __syncthreads();
    mx = fmaxf(fmaxf(redm[0], redm[1]), fmaxf(redm[2], redm[3]));

    float sum = 0.f;
    #pragma unroll
    for (int j = 0; j < 16; j++) { float e = __expf(v[j] - mx); v[j] = e; sum += e; }
    #pragma unroll
    for (int off = 32; off; off >>= 1) sum += __shfl_xor(sum, off);
    if (lane == 0) reds[wave] = sum;
    __syncthreads();
    sum = reds[0] + reds[1] + reds[2] + reds[3];
    const float inv = 1.f / sum;

    bf16x8 oa, ob;
    #pragma unroll
    for (int j = 0; j < 8; j++) { oa[j] = (__bf16)(v[j] * inv); ob[j] = (__bf16)(v[j + 8] * inv); }
    rowp[2 * tid] = oa;
    rowp[2 * tid + 1] = ob;
}

// (sum of NP partials) + residual (+ optional col-bias) -> LayerNorm(D=256)
template<int NP>
__launch_bounds__(256)
__global__ void ln_res(const float* __restrict__ p, long pstr,
                       const float* __restrict__ resid, const float* __restrict__ bias,
                       const float* __restrict__ gamma, const float* __restrict__ beta,
                       float* __restrict__ outf, __bf16* __restrict__ outb)
{
    const int row  = blockIdx.x * 4 + (threadIdx.x >> 6);
    const int lane = threadIdx.x & 63;
    const long vi = (long)row * 64 + lane;
    float4 vr = ((const float4*)resid)[vi];
    float x0 = vr.x, x1 = vr.y, x2 = vr.z, x3 = vr.w;
    #pragma unroll
    for (int i = 0; i < NP; i++) {
        float4 vp = ((const float4*)(p + (long)i * pstr))[vi];
        x0 += vp.x; x1 += vp.y; x2 += vp.z; x3 += vp.w;
    }
    if (bias) {
        float4 vb = ((const float4*)bias)[lane];
        x0 += vb.x; x1 += vb.y; x2 += vb.z; x3 += vb.w;
    }
    float s = x0 + x1 + x2 + x3;
    #pragma unroll
    for (int off = 32; off; off >>= 1) s += __shfl_xor(s, off);
    const float mu = s * (1.f / 256.f);
    float d0 = x0 - mu, d1 = x1 - mu, d2 = x2 - mu, d3 = x3 - mu;
    float s2 = d0 * d0 + d1 * d1 + d2 * d2 + d3 * d3;
    #pragma unroll
    for (int off = 32; off; off >>= 1) s2 += __shfl_xor(s2, off);
    const float rs = rsqrtf(s2 * (1.f / 256.f) + 1e-3f);
    const float4 g  = ((const float4*)gamma)[lane];
    const float4 be = ((const float4*)beta)[lane];
    float o0 = d0 * rs * g.x + be.x, o1 = d1 * rs * g.y + be.y;
    float o2 = d2 * rs * g.z + be.z, o3 = d3 * rs * g.w + be.w;
    float4 o; o.x = o0; o.y = o1; o.z = o2; o.w = o3;
    ((float4*)outf)[vi] = o;
    if (outb) {
        bf16x4 ob; ob[0] = (__bf16)o0; ob[1] = (__bf16)o1; ob[2] = (__bf16)o2; ob[3] = (__bf16)o3;
        ((bf16x4*)outb)[vi] = ob;
    }
}

__global__ void f2b4(const float4* __restrict__ in, bf16x4* __restrict__ out, long n4)
{
    long i = (long)blockIdx.x * blockDim.x + threadIdx.x;
    if (i < n4) {
        float4 v = in[i];
        bf16x4 o; o[0] = (__bf16)v.x; o[1] = (__bf16)v.y; o[2] = (__bf16)v.z; o[3] = (__bf16)v.w;
        out[i] = o;
    }
}

__global__ void transpose_pad(const float* __restrict__ src, __bf16* __restrict__ dst,
                              int rows, int cols, int rowsP, int colsP)
{
    int i = blockIdx.x * 256 + threadIdx.x;
    if (i >= rowsP * colsP) return;
    int c = i / rowsP, r = i % rowsP;
    float v = (r < rows && c < cols) ? src[r * cols + c] : 0.f;
    dst[i] = (__bf16)v;
}

__global__ void pad_bias(const float* __restrict__ b, float* __restrict__ bp, int n, int np)
{
    int i = blockIdx.x * 256 + threadIdx.x;
    if (i < np) bp[i] = (i < n) ? b[i] : 0.f;
}

__global__ void transpose_bf(const __bf16* __restrict__ in, __bf16* __restrict__ out,
                             int rows, int cols)
{
    __shared__ __bf16 t[32][33];
    const long base = (long)blockIdx.z * rows * cols;
    const int c0 = blockIdx.x * 32, r0 = blockIdx.y * 32;
    const int tx = threadIdx.x & 31, ty = threadIdx.x >> 5;
    #pragma unroll
    for (int i = 0; i < 32; i += 8)
        t[ty + i][tx] = in[base + (long)(r0 + ty + i) * cols + (c0 + tx)];
    __syncthreads();
    #pragma unroll
    for (int i = 0; i < 32; i += 8)
        out[base + (long)(c0 + ty + i) * rows + (r0 + tx)] = t[tx][ty + i];
}

extern "C" void kernel_launch(void* const* d_in, const int* in_sizes, int n_in,
                              void* d_out, int out_size, void* d_ws, size_t ws_size,
                              hipStream_t stream)
{
    constexpr int B = 4, S = 4096, D = 256, H = 400, Hp = 512;
    constexpr int R = B * S;
    constexpr float SCALE = 1.f / 64.f;   // 1/sqrt(4096)

    const float* inputs = (const float*)d_in[0];
    const float* ctx    = (const float*)d_in[1];
    const float* sa_Wk  = (const float*)d_in[2];
    const float* sa_Wv  = (const float*)d_in[3];
    const float* sa_Wq  = (const float*)d_in[4];
    const float* ca_Wk  = (const float*)d_in[5];
    const float* ca_Wv  = (const float*)d_in[6];
    const float* ca_Wq  = (const float*)d_in[7];
    const float* W1     = (const float*)d_in[8];
    const float* b1     = (const float*)d_in[9];
    const float* W2     = (const float*)d_in[10];
    const float* b2     = (const float*)d_in[11];
    const float* gamma  = (const float*)d_in[12];
    const float* beta   = (const float*)d_in[13];
    float* out = (float*)d_out;

    char* ws = (char*)d_ws;
    size_t off = 0;
    auto alloc = [&](size_t bytes) -> char* {
        char* p = ws + off; off += (bytes + 255) & ~size_t(255); return p;
    };
    __bf16* bfA  = (__bf16*)alloc((size_t)R * D * 2);     // bf16(inputs) -> xbf
    __bf16* bfC  = (__bf16*)alloc((size_t)R * D * 2);     // bf16(context) -> ybf
    __bf16* Qb   = (__bf16*)alloc((size_t)R * D * 2);
    __bf16* Kb   = (__bf16*)alloc((size_t)R * D * 2);
    __bf16* Vt   = (__bf16*)alloc((size_t)B * D * S * 2); // [B][D][S]
    __bf16* h    = (__bf16*)alloc((size_t)R * Hp * 2);    // FFN hidden / Vtmp
    float*  x    = (float*)alloc((size_t)R * D * 4);
    float*  y    = (float*)alloc((size_t)R * D * 4);
    __bf16* wqkv_s = (__bf16*)alloc((size_t)3 * D * D * 2);  // [Wq^T | Wk^T | Wv^T]
    __bf16* wkv_c  = (__bf16*)alloc((size_t)2 * D * D * 2);  // [Wk^T | Wv^T]
    __bf16* wq_c   = (__bf16*)alloc((size_t)D * D * 2);
    __bf16* W1t  = (__bf16*)alloc((size_t)Hp * D * 2);
    __bf16* W2t  = (__bf16*)alloc((size_t)D * Hp * 2);
    float*  b1p  = (float*)alloc((size_t)Hp * 4);

    const size_t PB  = (size_t)R * D * 4;
    const size_t SCB = (size_t)B * S * S * 2;
    const size_t SCs = (size_t)S * S * 2;
    size_t rem = ws_size > off ? ws_size - off : 0;
    int NS; bool batched = true;
    if      (rem >= 4 * PB + SCB) NS = 4;
    else if (rem >= 2 * PB + SCB) NS = 2;
    else if (rem >= 1 * PB + SCB) NS = 1;
    else { batched = false; NS = (rem >= 4 * PB + SCs) ? 4 : 1; }
    float*  pbuf = (float*)alloc((size_t)NS * PB);
    __bf16* SC   = (__bf16*)(ws + off);
    const long PBe = (long)R * D;
    const int NS2 = NS >= 2 ? 2 : 1;

    __bf16* xbf  = bfA;
    __bf16* ybf  = bfC;
    __bf16* Vtmp = h;

    const dim3 blk(256);
    const dim3 gT(D / 32, S / 32, B);

    auto launch_ln = [&](int np, const float* res, const float* bias,
                         float* of, __bf16* ob) {
        if (np == 4)      ln_res<4><<<R / 4, blk, 0, stream>>>(pbuf, PBe, res, bias, gamma, beta, of, ob);
        else if (np == 2) ln_res<2><<<R / 4, blk, 0, stream>>>(pbuf, PBe, res, bias, gamma, beta, of, ob);
        else              ln_res<1><<<R / 4, blk, 0, stream>>>(pbuf, PBe, res, bias, gamma, beta, of, ob);
    };

    // --- prep ---
    f2b4<<<R * D / 1024, blk, 0, stream>>>((const float4*)inputs, (bf16x4*)bfA, (long)R * D / 4);
    f2b4<<<R * D / 1024, blk, 0, stream>>>((const float4*)ctx,    (bf16x4*)bfC, (long)R * D / 4);
    transpose_pad<<<(D * D + 255) / 256, blk, 0, stream>>>(sa_Wq, wqkv_s,             D, D, D, D);
    transpose_pad<<<(D * D + 255) / 256, blk, 0, stream>>>(sa_Wk, wqkv_s + D * D,     D, D, D, D);
    transpose_pad<<<(D * D + 255) / 256, blk, 0, stream>>>(sa_Wv, wqkv_s + 2 * D * D, D, D, D, D);
    transpose_pad<<<(D * D + 255) / 256, blk, 0, stream>>>(ca_Wk, wkv_c,              D, D, D, D);
    transpose_pad<<<(D * D + 255) / 256, blk, 0, stream>>>(ca_Wv, wkv_c + D * D,      D, D, D, D);
    transpose_pad<<<(D * D + 255) / 256, blk, 0, stream>>>(ca_Wq, wq_c,               D, D, D, D);
    transpose_pad<<<(Hp * D + 255) / 256, blk, 0, stream>>>(W1, W1t, D, H, D, Hp);
    transpose_pad<<<(D * Hp + 255) / 256, blk, 0, stream>>>(W2, W2t, H, D, Hp, D);
    pad_bias<<<2, blk, 0, stream>>>(b1, b1p, H, Hp);

    // --- self-attention (causal): fused QKV projection ---
    gemm_nt<4, 0><<<dim3(6, 128, 1), blk, 0, stream>>>(bfA, wqkv_s, nullptr, Qb, Kb, Vtmp,
                                                       3 * D, D, 0, 0, 0, 6, D, 0);
    transpose_bf<<<gT, blk, 0, stream>>>(Vtmp, Vt, S, D);
    if (batched) {
        gemm_nt<1, 1><<<dim3(32, 32, B), blk, 0, stream>>>(Qb, Kb, nullptr, SC, nullptr, nullptr,
                                                           S, D, (long)S * D, (long)S * D, (long)S * S, 32, D, 0);
        softmax_inplace<true><<<dim3(S, B), blk, 0, stream>>>(SC, SCALE);
        gemm_nt<0, 2><<<dim3(2 * NS, 32, B), blk, 0, stream>>>(SC, Vt, nullptr, pbuf, nullptr, nullptr,
                                                               D, S, (long)S * S, (long)D * S, (long)S * D,
                                                               2, S / NS, (long)PB);
    } else {
        for (int b = 0; b < B; b++) {
            gemm_nt<1, 1><<<dim3(32, 32, 1), blk, 0, stream>>>(Qb + (long)b * S * D, Kb + (long)b * S * D,
                                                               nullptr, SC, nullptr, nullptr,
                                                               S, D, 0, 0, 0, 32, D, 0);
            softmax_inplace<true><<<dim3(S, 1), blk, 0, stream>>>(SC, SCALE);
            gemm_nt<0, 2><<<dim3(2 * NS, 32, 1), blk, 0, stream>>>(SC, Vt + (long)b * D * S, nullptr,
                                                                   pbuf + (long)b * S * D, nullptr, nullptr,
                                                                   D, S, 0, 0, 0, 2, S / NS, (long)PB);
        }
    }
    launch_ln(NS, inputs, nullptr, x, xbf);

    // --- cross-attention (full): Q from x, fused KV from context ---
    gemm_nt<1, 0><<<dim3(2, 128, 1), blk, 0, stream>>>(xbf, wq_c, nullptr, Qb, nullptr, nullptr,
                                                       D, D, 0, 0, 0, 2, D, 0);
    gemm_nt<4, 0><<<dim3(4, 128, 1), blk, 0, stream>>>(bfC, wkv_c, nullptr, Kb, Vtmp, nullptr,
                                                       2 * D, D, 0, 0, 0, 4, D, 0);
    transpose_bf<<<gT, blk, 0, stream>>>(Vtmp, Vt, S, D);
    if (batched) {
        gemm_nt<1, 0><<<dim3(32, 32, B), blk, 0, stream>>>(Qb, Kb, nullptr, SC, nullptr, nullptr,
                                                           S, D, (long)S * D, (long)S * D, (long)S * S, 32, D, 0);
        softmax_inplace<false><<<dim3(S, B), blk, 0, stream>>>(SC, SCALE);
        gemm_nt<0, 0><<<dim3(2 * NS, 32, B), blk, 0, stream>>>(SC, Vt, nullptr, pbuf, nullptr, nullptr,
                                                               D, S, (long)S * S, (long)D * S, (long)S * D,
                                                               2, S / NS, (long)PB);
    } else {
        for (int b = 0; b < B; b++) {
            gemm_nt<1, 0><<<dim3(32, 32, 1), blk, 0, stream>>>(Qb + (long)b * S * D, Kb + (long)b * S * D,
                                                               nullptr, SC, nullptr, nullptr,
                                                               S, D, 0, 0, 0, 32, D, 0);
            softmax_inplace<false><<<dim3(S, 1), blk, 0, stream>>>(SC, SCALE);
            gemm_nt<0, 0><<<dim3(2 * NS, 32, 1), blk, 0, stream>>>(SC, Vt + (long)b * D * S, nullptr,
                                                                   pbuf + (long)b * S * D, nullptr, nullptr,
                                                                   D, S, 0, 0, 0, 2, S / NS, (long)PB);
        }
    }
    launch_ln(NS, x, nullptr, y, ybf);

    // --- FFN ---
    gemm_nt<2, 0><<<dim3(4, 128, 1), blk, 0, stream>>>(ybf, W1t, b1p, h, nullptr, nullptr,
                                                       Hp, D, 0, 0, 0, 4, D, 0);
    gemm_nt<0, 0><<<dim3(2 * NS2, 128, 1), blk, 0, stream>>>(h, W2t, nullptr, pbuf, nullptr, nullptr,
                                                             D, Hp, 0, 0, 0, 2, Hp / NS2, (long)PB);
    launch_ln(NS2, y, b2, out, nullptr);   // b2 folded into pre-LN sum
}